// Round 1
// baseline (175.334 us; speedup 1.0000x reference)
//
#include <hip/hip_runtime.h>

#define HWD 256
#define NB 2
#define NV 5023
#define NF 2048

struct FaceRec {            // 48 bytes, 16B-aligned usage
    float dy12, dx21, x2, y2;
    float dy20, dx02, inv, z0;
    float z1, z2;
    unsigned int bbx;       // xlo | (xhi<<16)
    unsigned int bby;       // ylo | (yhi<<16)
};

__device__ __forceinline__ float pix_coord(int i) {
    // ((i + 0.5)/256)*2 - 1  ; exact in fp32 for i in [0,255]
    return ((float)i + 0.5f) * 0.0078125f - 1.0f;
}

__device__ __forceinline__ unsigned int z_order(float z) {
    unsigned int b = __float_as_uint(z);
    return (b & 0x80000000u) ? ~b : (b | 0x80000000u);
}

__global__ __launch_bounds__(256) void k_init(unsigned long long* zk) {
    int i = blockIdx.x * 256 + threadIdx.x;
    // empty: z=-1.0 -> ordered 0x407FFFFF ; lo = 0x80000000 (beats any real face at z==-1.0)
    zk[i] = (0x407FFFFFull << 32) | 0x80000000ull;
}

__global__ __launch_bounds__(256) void k_vattr(const float* __restrict__ verts,
                                               const float* __restrict__ tex,
                                               const float* __restrict__ uv,
                                               float* __restrict__ vattr) {
    int i = blockIdx.x * 256 + threadIdx.x;
    if (i >= NB * NV) return;
    int b = i / NV, v = i - b * NV;
    float u = __fmul_rn(uv[2 * v + 0], 255.0f);
    float w = __fmul_rn(uv[2 * v + 1], 255.0f);
    float uf = floorf(u); uf = fminf(fmaxf(uf, 0.0f), 254.0f);
    float vf = floorf(w); vf = fminf(fmaxf(vf, 0.0f), 254.0f);
    int u0 = (int)uf, v0 = (int)vf;
    float fu = __fsub_rn(u, uf);
    float fv = __fsub_rn(w, vf);
    const float* t  = tex + (size_t)b * HWD * HWD * 3;
    const float* c00 = t + ((size_t)v0 * HWD + u0) * 3;
    const float* c01 = c00 + 3;
    const float* c10 = c00 + HWD * 3;
    const float* c11 = c10 + 3;
    float gu = 1.0f - fu, gv = 1.0f - fv;
    float* o = vattr + (size_t)i * 6;
    for (int c = 0; c < 3; ++c) {
        float l0 = c00[c] * gu + c01[c] * fu;
        float l1 = c10[c] * gu + c11[c] * fu;
        o[c] = l0 * gv + l1 * fv;
    }
    const float* vp = verts + ((size_t)b * NV + v) * 3;
    o[3] = vp[0]; o[4] = vp[1]; o[5] = vp[2];
}

__global__ __launch_bounds__(256) void k_setup(const float* __restrict__ tv,
                                               const int* __restrict__ faces,
                                               FaceRec* __restrict__ fr) {
    int i = blockIdx.x * 256 + threadIdx.x;
    if (i >= NB * NF) return;
    int b = i / NF, f = i - b * NF;
    int i0 = faces[3 * f + 0], i1 = faces[3 * f + 1], i2 = faces[3 * f + 2];
    const float* base = tv + (size_t)b * NV * 3;
    float x0 = base[3 * i0 + 0], y0 = base[3 * i0 + 1], z0 = base[3 * i0 + 2];
    float x1 = base[3 * i1 + 0], y1 = base[3 * i1 + 1], z1 = base[3 * i1 + 2];
    float x2 = base[3 * i2 + 0], y2 = base[3 * i2 + 1], z2 = base[3 * i2 + 2];

    float dy12 = __fsub_rn(y1, y2);
    float dx21 = __fsub_rn(x2, x1);
    float dy20 = __fsub_rn(y2, y0);
    float dx02 = __fsub_rn(x0, x2);
    // denom = (y1-y2)*(x0-x2) + (x2-x1)*(y0-y2)  -- exact reference op order
    float denom = __fadd_rn(__fmul_rn(dy12, __fsub_rn(x0, x2)),
                            __fmul_rn(dx21, __fsub_rn(y0, y2)));
    bool valid = fabsf(denom) > 1e-8f;

    FaceRec r;
    r.dy12 = dy12; r.dx21 = dx21; r.x2 = x2; r.y2 = y2;
    r.dy20 = dy20; r.dx02 = dx02;
    r.inv = valid ? (1.0f / denom) : 0.0f;
    r.z0 = z0; r.z1 = z1; r.z2 = z2;

    int xlo = 1, xhi = 0, ylo = 1, yhi = 0;   // empty by default
    if (valid) {
        if (fabsf(denom) < 1e-3f) {
            xlo = 0; xhi = 255; ylo = 0; yhi = 255;   // near-degenerate: be conservative
        } else {
            float xmn = fminf(x0, fminf(x1, x2)), xmx = fmaxf(x0, fmaxf(x1, x2));
            float ymn = fminf(y0, fminf(y1, y2)), ymx = fmaxf(y0, fmaxf(y1, y2));
            xlo = (int)floorf((xmn + 1.0f) * 128.0f - 0.5f) - 1;
            xhi = (int)ceilf ((xmx + 1.0f) * 128.0f - 0.5f) + 1;
            ylo = (int)floorf((ymn + 1.0f) * 128.0f - 0.5f) - 1;
            yhi = (int)ceilf ((ymx + 1.0f) * 128.0f - 0.5f) + 1;
            xlo = max(xlo, 0); ylo = max(ylo, 0);
            xhi = min(xhi, 255); yhi = min(yhi, 255);
            if (xhi < xlo || yhi < ylo) { xlo = 1; xhi = 0; ylo = 1; yhi = 0; }
        }
    }
    r.bbx = (unsigned)xlo | ((unsigned)xhi << 16);
    r.bby = (unsigned)ylo | ((unsigned)yhi << 16);
    fr[i] = r;
}

__global__ __launch_bounds__(256) void k_raster(const FaceRec* __restrict__ fr,
                                                unsigned long long* __restrict__ zk) {
    int blk = blockIdx.x;            // b*NF + f
    int f = blk & (NF - 1);
    int b = blk >> 11;
    FaceRec r = fr[blk];
    int xlo = (int)(r.bbx & 0xffffu), xhi = (int)(r.bbx >> 16);
    int ylo = (int)(r.bby & 0xffffu), yhi = (int)(r.bby >> 16);
    if (xhi < xlo || yhi < ylo) return;

    unsigned long long* zb = zk + (size_t)b * HWD * HWD;
    unsigned int lokey = 0x7FFFFFFFu - (unsigned int)f;
    int tx = threadIdx.x & 15, ty = threadIdx.x >> 4;

    for (int py = ylo + ty; py <= yhi; py += 16) {
        float yf = pix_coord(py);
        float t1 = __fsub_rn(yf, r.y2);
        for (int px = xlo + tx; px <= xhi; px += 16) {
            float xf = pix_coord(px);
            float t0 = __fsub_rn(xf, r.x2);
            float w0 = __fmul_rn(__fadd_rn(__fmul_rn(r.dy12, t0), __fmul_rn(r.dx21, t1)), r.inv);
            float w1 = __fmul_rn(__fadd_rn(__fmul_rn(r.dy20, t0), __fmul_rn(r.dx02, t1)), r.inv);
            float w2 = __fsub_rn(__fsub_rn(1.0f, w0), w1);
            if (w0 >= 0.0f && w1 >= 0.0f && w2 >= 0.0f) {
                float z = __fadd_rn(__fadd_rn(__fmul_rn(w0, r.z0), __fmul_rn(w1, r.z1)),
                                    __fmul_rn(w2, r.z2));
                unsigned long long key = ((unsigned long long)z_order(z) << 32) | lokey;
                int pix = py * HWD + px;
                unsigned long long cur = zb[pix];   // monotone buffer: stale-read safe
                if (key > cur) atomicMax(&zb[pix], key);
            }
        }
    }
}

__global__ __launch_bounds__(256) void k_shade(const unsigned long long* __restrict__ zk,
                                               const FaceRec* __restrict__ fr,
                                               const int* __restrict__ faces,
                                               const float* __restrict__ vattr,
                                               float* __restrict__ out) {
    int i = blockIdx.x * 256 + threadIdx.x;   // 0 .. B*H*W-1
    int b = i >> 16;
    int pix = i & 0xFFFF;
    unsigned long long key = zk[i];
    unsigned int lo = (unsigned int)key;
    unsigned int hi = (unsigned int)(key >> 32);

    float img[6] = {0, 0, 0, 0, 0, 0};
    float alpha, fidf, zout;
    if (lo > 0x7FFFFFFFu) {          // empty pixel
        alpha = 0.0f; fidf = -1.0f; zout = -1.0f;
    } else {
        int f = (int)(0x7FFFFFFFu - lo);
        unsigned int zb32 = (hi & 0x80000000u) ? (hi & 0x7FFFFFFFu) : ~hi;
        zout = __uint_as_float(zb32);
        alpha = 1.0f;
        fidf = (float)f;
        FaceRec r = fr[b * NF + f];
        int px = pix & 0xFF, py = pix >> 8;
        float t0 = __fsub_rn(pix_coord(px), r.x2);
        float t1 = __fsub_rn(pix_coord(py), r.y2);
        float w0 = __fmul_rn(__fadd_rn(__fmul_rn(r.dy12, t0), __fmul_rn(r.dx21, t1)), r.inv);
        float w1 = __fmul_rn(__fadd_rn(__fmul_rn(r.dy20, t0), __fmul_rn(r.dx02, t1)), r.inv);
        float w2 = __fsub_rn(__fsub_rn(1.0f, w0), w1);
        int i0 = faces[3 * f + 0], i1 = faces[3 * f + 1], i2 = faces[3 * f + 2];
        const float* a0 = vattr + ((size_t)b * NV + i0) * 6;
        const float* a1 = vattr + ((size_t)b * NV + i1) * 6;
        const float* a2 = vattr + ((size_t)b * NV + i2) * 6;
        for (int c = 0; c < 6; ++c)
            img[c] = __fadd_rn(__fadd_rn(__fmul_rn(w0, a0[c]), __fmul_rn(w1, a1[c])),
                               __fmul_rn(w2, a2[c]));
    }

    const size_t plane = (size_t)HWD * HWD;
    for (int c = 0; c < 6; ++c)
        out[((size_t)b * 6 + c) * plane + pix] = img[c];
    out[786432 + i]  = alpha;   // alpha_images (B,1,H,W)
    out[917504 + i]  = fidf;    // fid as float
    out[1048576 + i] = zout;    // zbuf
}

extern "C" void kernel_launch(void* const* d_in, const int* in_sizes, int n_in,
                              void* d_out, int out_size, void* d_ws, size_t ws_size,
                              hipStream_t stream) {
    (void)in_sizes; (void)n_in; (void)out_size; (void)ws_size;
    const float* verts = (const float*)d_in[0];
    const float* tv    = (const float*)d_in[1];
    const float* tex   = (const float*)d_in[2];
    const float* uv    = (const float*)d_in[3];
    const int*   faces = (const int*)d_in[4];
    float* out = (float*)d_out;

    char* ws = (char*)d_ws;
    unsigned long long* zk = (unsigned long long*)ws;            // 1 MiB (B*H*W * 8B)
    float* vattr = (float*)(ws + (1 << 20));                     // 241 KB
    FaceRec* fr  = (FaceRec*)(ws + (1 << 20) + (5 << 16));       // 192 KB, 16B aligned

    k_init  <<<512, 256, 0, stream>>>(zk);
    k_vattr <<<(NB * NV + 255) / 256, 256, 0, stream>>>(verts, tex, uv, vattr);
    k_setup <<<(NB * NF + 255) / 256, 256, 0, stream>>>(tv, faces, fr);
    k_raster<<<NB * NF, 256, 0, stream>>>(fr, zk);
    k_shade <<<512, 256, 0, stream>>>(zk, fr, faces, vattr, out);
}

// Round 2
// 168.590 us; speedup vs baseline: 1.0400x; 1.0400x over previous
//
#include <hip/hip_runtime.h>

#define HWD 256
#define NB 2
#define NV 5023
#define NF 2048
#define NTILE 512          // 2 batches * 16*16 tiles of 16x16 px
#define CAP 2048           // exact worst case: every face in a tile
#define SEG 8              // segments per tile list

__device__ __forceinline__ float pix_coord(int i) {
    return ((float)i + 0.5f) * 0.0078125f - 1.0f;   // exact fp32
}

__device__ __forceinline__ unsigned int z_order(float z) {
    unsigned int b = __float_as_uint(z);
    return (b & 0x80000000u) ? ~b : (b | 0x80000000u);
}

// ws layout
//  zk    @ 0x000000  131072 * 8B = 1 MiB
//  frP   @ 0x100000  NB*NF * 64B = 256 KiB   (16 floats per face)
//  vattr @ 0x140000  NB*NV*6*4   = 241 KiB (padded to 256 KiB)
//  cnt   @ 0x180000  512 * 4B              (padded to 4 KiB)
//  list  @ 0x181000  512 * 2048 * 2B = 2 MiB

__global__ __launch_bounds__(256) void k_init(unsigned long long* zk, unsigned int* cnt) {
    int i = blockIdx.x * 256 + threadIdx.x;
    zk[i] = (0x407FFFFFull << 32) | 0x80000000ull;   // z=-1.0, "no face"
    if (i < NTILE) cnt[i] = 0;
}

__global__ __launch_bounds__(256) void k_vattr(const float* __restrict__ verts,
                                               const float* __restrict__ tex,
                                               const float* __restrict__ uv,
                                               float* __restrict__ vattr) {
    int i = blockIdx.x * 256 + threadIdx.x;
    if (i >= NB * NV) return;
    int b = i / NV, v = i - b * NV;
    float u = __fmul_rn(uv[2 * v + 0], 255.0f);
    float w = __fmul_rn(uv[2 * v + 1], 255.0f);
    float uf = floorf(u); uf = fminf(fmaxf(uf, 0.0f), 254.0f);
    float vf = floorf(w); vf = fminf(fmaxf(vf, 0.0f), 254.0f);
    int u0 = (int)uf, v0 = (int)vf;
    float fu = __fsub_rn(u, uf);
    float fv = __fsub_rn(w, vf);
    const float* t   = tex + (size_t)b * HWD * HWD * 3;
    const float* c00 = t + ((size_t)v0 * HWD + u0) * 3;
    const float* c01 = c00 + 3;
    const float* c10 = c00 + HWD * 3;
    const float* c11 = c10 + 3;
    float gu = 1.0f - fu, gv = 1.0f - fv;
    float* o = vattr + (size_t)i * 6;
    for (int c = 0; c < 3; ++c) {
        float l0 = c00[c] * gu + c01[c] * fu;
        float l1 = c10[c] * gu + c11[c] * fu;
        o[c] = l0 * gv + l1 * fv;
    }
    const float* vp = verts + ((size_t)b * NV + v) * 3;
    o[3] = vp[0]; o[4] = vp[1]; o[5] = vp[2];
}

// frP fields: 0 dy12, 1 dx21, 2 x2, 3 y2, 4 dy20, 5 dx02, 6 inv, 7 z0, 8 z1, 9 z2,
//             10 bbx bits, 11 bby bits, 12 denom, 13..15 pad
__global__ __launch_bounds__(256) void k_setup(const float* __restrict__ tv,
                                               const int* __restrict__ faces,
                                               float* __restrict__ frP) {
    int i = blockIdx.x * 256 + threadIdx.x;
    if (i >= NB * NF) return;
    int b = i / NF, f = i - b * NF;
    int i0 = faces[3 * f + 0], i1 = faces[3 * f + 1], i2 = faces[3 * f + 2];
    const float* base = tv + (size_t)b * NV * 3;
    float x0 = base[3 * i0 + 0], y0 = base[3 * i0 + 1], z0 = base[3 * i0 + 2];
    float x1 = base[3 * i1 + 0], y1 = base[3 * i1 + 1], z1 = base[3 * i1 + 2];
    float x2 = base[3 * i2 + 0], y2 = base[3 * i2 + 1], z2 = base[3 * i2 + 2];

    float dy12 = __fsub_rn(y1, y2);
    float dx21 = __fsub_rn(x2, x1);
    float dy20 = __fsub_rn(y2, y0);
    float dx02 = __fsub_rn(x0, x2);
    float denom = __fadd_rn(__fmul_rn(dy12, __fsub_rn(x0, x2)),
                            __fmul_rn(dx21, __fsub_rn(y0, y2)));
    bool valid = fabsf(denom) > 1e-8f;

    int xlo = 1, xhi = 0, ylo = 1, yhi = 0;
    if (valid) {
        if (fabsf(denom) < 1e-3f) {
            xlo = 0; xhi = 255; ylo = 0; yhi = 255;
        } else {
            float xmn = fminf(x0, fminf(x1, x2)), xmx = fmaxf(x0, fmaxf(x1, x2));
            float ymn = fminf(y0, fminf(y1, y2)), ymx = fmaxf(y0, fmaxf(y1, y2));
            xlo = (int)floorf((xmn + 1.0f) * 128.0f - 0.5f) - 1;
            xhi = (int)ceilf ((xmx + 1.0f) * 128.0f - 0.5f) + 1;
            ylo = (int)floorf((ymn + 1.0f) * 128.0f - 0.5f) - 1;
            yhi = (int)ceilf ((ymx + 1.0f) * 128.0f - 0.5f) + 1;
            xlo = max(xlo, 0); ylo = max(ylo, 0);
            xhi = min(xhi, 255); yhi = min(yhi, 255);
            if (xhi < xlo || yhi < ylo) { xlo = 1; xhi = 0; ylo = 1; yhi = 0; }
        }
    }
    float* o = frP + (size_t)i * 16;
    o[0] = dy12; o[1] = dx21; o[2] = x2; o[3] = y2;
    o[4] = dy20; o[5] = dx02; o[6] = valid ? (1.0f / denom) : 0.0f;
    o[7] = z0; o[8] = z1; o[9] = z2;
    ((unsigned int*)o)[10] = (unsigned)xlo | ((unsigned)xhi << 16);
    ((unsigned int*)o)[11] = (unsigned)ylo | ((unsigned)yhi << 16);
    o[12] = denom;
}

// bin faces into per-tile lists (conservative triangle-vs-tile test)
__global__ __launch_bounds__(256) void k_bin(const float* __restrict__ frP,
                                             unsigned int* __restrict__ cnt,
                                             unsigned short* __restrict__ list) {
    int gi = blockIdx.x * 4 + (threadIdx.x >> 6);   // face global idx
    int lane = threadIdx.x & 63;
    int b = gi >> 11, f = gi & (NF - 1);
    const float* o = frP + (size_t)gi * 16;
    unsigned int bbx = ((const unsigned int*)o)[10];
    unsigned int bby = ((const unsigned int*)o)[11];
    int xlo = (int)(bbx & 0xffffu), xhi = (int)(bbx >> 16);
    int ylo = (int)(bby & 0xffffu), yhi = (int)(bby >> 16);
    if (xhi < xlo || yhi < ylo) return;

    int txlo = xlo >> 4, txhi = xhi >> 4;
    int tylo = ylo >> 4, tyhi = yhi >> 4;
    int ntx = txhi - txlo + 1, nty = tyhi - tylo + 1;
    int total = ntx * nty;

    float inv = o[6], denom = o[12];
    bool skipTest = fabsf(denom) < 1e-3f;
    float x2 = o[2], y2 = o[3];
    float A0 = o[0] * inv, B0 = o[1] * inv;   // w0 = A0*(x-x2)+B0*(y-y2)
    float A1 = o[4] * inv, B1 = o[5] * inv;   // w1
    float C  = A0 + A1,    D  = B0 + B1;      // w0+w1

    for (int t = lane; t < total; t += 64) {
        int ty = tylo + t / ntx;
        int tx = txlo + t - (t / ntx) * ntx;
        bool keep = true;
        if (!skipTest) {
            float x0n = pix_coord(tx * 16), x1n = pix_coord(tx * 16 + 15);
            float y0n = pix_coord(ty * 16), y1n = pix_coord(ty * 16 + 15);
            float w0m = A0 * ((A0 > 0.f ? x1n : x0n) - x2) + B0 * ((B0 > 0.f ? y1n : y0n) - y2);
            float w1m = A1 * ((A1 > 0.f ? x1n : x0n) - x2) + B1 * ((B1 > 0.f ? y1n : y0n) - y2);
            float w2m = 1.0f - (C * ((C > 0.f ? x0n : x1n) - x2) + D * ((D > 0.f ? y0n : y1n) - y2));
            const float eps = 0.02f;
            keep = (w0m >= -eps) && (w1m >= -eps) && (w2m >= -eps);
        }
        if (keep) {
            int tile = b * 256 + ty * 16 + tx;
            unsigned int slot = atomicAdd(&cnt[tile], 1u);
            if (slot < CAP) list[(size_t)tile * CAP + slot] = (unsigned short)f;
        }
    }
}

__global__ __launch_bounds__(256) void k_raster(const float* __restrict__ frP,
                                                const unsigned int* __restrict__ cnt,
                                                const unsigned short* __restrict__ list,
                                                unsigned long long* __restrict__ zk) {
    int bid = blockIdx.x;
    int seg  = bid >> 9;            // 0..SEG-1
    int tile = bid & (NTILE - 1);
    int b = tile >> 8, t = tile & 255;
    int tx0 = (t & 15) * 16, ty0 = (t >> 4) * 16;

    unsigned int count = cnt[tile];
    unsigned int begin = (count * (unsigned)seg) / SEG;
    unsigned int end   = (count * (unsigned)(seg + 1)) / SEG;
    if (begin >= end) return;

    int px = tx0 + (threadIdx.x & 15);
    int py = ty0 + (threadIdx.x >> 4);
    float pxf = pix_coord(px), pyf = pix_coord(py);

    __shared__ float fdat[64 * 12];
    __shared__ unsigned short fidxs[64];
    const unsigned short* lst = list + (size_t)tile * CAP;
    const float* frB = frP + ((size_t)b * NF) * 16;

    unsigned long long best = 0ull;

    for (unsigned int cbase = begin; cbase < end; cbase += 64) {
        int n = min(64u, end - cbase);
        __syncthreads();
        for (int idx = threadIdx.x; idx < n * 12; idx += 256) {
            int face = idx / 12;
            int field = idx - face * 12;
            int gf = lst[cbase + face];
            fdat[idx] = frB[(size_t)gf * 16 + field];
        }
        if (threadIdx.x < n) fidxs[threadIdx.x] = lst[cbase + threadIdx.x];
        __syncthreads();

        for (int j = 0; j < n; ++j) {
            const float* fp = &fdat[j * 12];
            float t0 = __fsub_rn(pxf, fp[2]);
            float t1 = __fsub_rn(pyf, fp[3]);
            float w0 = __fmul_rn(__fadd_rn(__fmul_rn(fp[0], t0), __fmul_rn(fp[1], t1)), fp[6]);
            float w1 = __fmul_rn(__fadd_rn(__fmul_rn(fp[4], t0), __fmul_rn(fp[5], t1)), fp[6]);
            float w2 = __fsub_rn(__fsub_rn(1.0f, w0), w1);
            if (w0 >= 0.0f && w1 >= 0.0f && w2 >= 0.0f) {
                float z = __fadd_rn(__fadd_rn(__fmul_rn(w0, fp[7]), __fmul_rn(w1, fp[8])),
                                    __fmul_rn(w2, fp[9]));
                unsigned long long key = ((unsigned long long)z_order(z) << 32)
                                       | (unsigned long long)(0x7FFFFFFFu - (unsigned int)fidxs[j]);
                best = (key > best) ? key : best;
            }
        }
    }

    if (best) {
        int pix = (b << 16) + py * HWD + px;
        unsigned long long cur = zk[pix];
        if (best > cur) atomicMax(&zk[pix], best);
    }
}

__global__ __launch_bounds__(256) void k_shade(const unsigned long long* __restrict__ zk,
                                               const float* __restrict__ frP,
                                               const int* __restrict__ faces,
                                               const float* __restrict__ vattr,
                                               float* __restrict__ out) {
    int i = blockIdx.x * 256 + threadIdx.x;
    int b = i >> 16;
    int pix = i & 0xFFFF;
    unsigned long long key = zk[i];
    unsigned int lo = (unsigned int)key;
    unsigned int hi = (unsigned int)(key >> 32);

    float img[6] = {0, 0, 0, 0, 0, 0};
    float alpha, fidf, zout;
    if (lo > 0x7FFFFFFFu) {
        alpha = 0.0f; fidf = -1.0f; zout = -1.0f;
    } else {
        int f = (int)(0x7FFFFFFFu - lo);
        unsigned int zb32 = (hi & 0x80000000u) ? (hi & 0x7FFFFFFFu) : ~hi;
        zout = __uint_as_float(zb32);
        alpha = 1.0f;
        fidf = (float)f;
        const float* fp = frP + ((size_t)(b * NF + f)) * 16;
        int px = pix & 0xFF, py = pix >> 8;
        float t0 = __fsub_rn(pix_coord(px), fp[2]);
        float t1 = __fsub_rn(pix_coord(py), fp[3]);
        float w0 = __fmul_rn(__fadd_rn(__fmul_rn(fp[0], t0), __fmul_rn(fp[1], t1)), fp[6]);
        float w1 = __fmul_rn(__fadd_rn(__fmul_rn(fp[4], t0), __fmul_rn(fp[5], t1)), fp[6]);
        float w2 = __fsub_rn(__fsub_rn(1.0f, w0), w1);
        int i0 = faces[3 * f + 0], i1 = faces[3 * f + 1], i2 = faces[3 * f + 2];
        const float* a0 = vattr + ((size_t)b * NV + i0) * 6;
        const float* a1 = vattr + ((size_t)b * NV + i1) * 6;
        const float* a2 = vattr + ((size_t)b * NV + i2) * 6;
        for (int c = 0; c < 6; ++c)
            img[c] = __fadd_rn(__fadd_rn(__fmul_rn(w0, a0[c]), __fmul_rn(w1, a1[c])),
                               __fmul_rn(w2, a2[c]));
    }

    const size_t plane = (size_t)HWD * HWD;
    for (int c = 0; c < 6; ++c)
        out[((size_t)b * 6 + c) * plane + pix] = img[c];
    out[786432 + i]  = alpha;
    out[917504 + i]  = fidf;
    out[1048576 + i] = zout;
}

extern "C" void kernel_launch(void* const* d_in, const int* in_sizes, int n_in,
                              void* d_out, int out_size, void* d_ws, size_t ws_size,
                              hipStream_t stream) {
    (void)in_sizes; (void)n_in; (void)out_size; (void)ws_size;
    const float* verts = (const float*)d_in[0];
    const float* tv    = (const float*)d_in[1];
    const float* tex   = (const float*)d_in[2];
    const float* uv    = (const float*)d_in[3];
    const int*   faces = (const int*)d_in[4];
    float* out = (float*)d_out;

    char* ws = (char*)d_ws;
    unsigned long long* zk   = (unsigned long long*)ws;               // 1 MiB
    float*              frP  = (float*)(ws + 0x100000);               // 256 KiB
    float*              vattr= (float*)(ws + 0x140000);               // 256 KiB
    unsigned int*       cnt  = (unsigned int*)(ws + 0x180000);        // 4 KiB
    unsigned short*     list = (unsigned short*)(ws + 0x181000);      // 2 MiB

    k_init  <<<512, 256, 0, stream>>>(zk, cnt);
    k_vattr <<<(NB * NV + 255) / 256, 256, 0, stream>>>(verts, tex, uv, vattr);
    k_setup <<<(NB * NF + 255) / 256, 256, 0, stream>>>(tv, faces, frP);
    k_bin   <<<NB * NF / 4, 256, 0, stream>>>(frP, cnt, list);
    k_raster<<<NTILE * SEG, 256, 0, stream>>>(frP, cnt, list, zk);
    k_shade <<<512, 256, 0, stream>>>(zk, frP, faces, vattr, out);
}

// Round 3
// 140.313 us; speedup vs baseline: 1.2496x; 1.2015x over previous
//
#include <hip/hip_runtime.h>

#define HWD 256
#define NB 2
#define NV 5023
#define NF 2048
#define NGRP 8            // face groups = raster segments
#define GRPSZ 256         // faces per group (NF/NGRP)
#define NT 256            // tiles per batch (16x16 tiles of 16x16 px)

// ws layout:
//  zk    @ 0x000000  131072 * 8B = 1 MiB
//  frP   @ 0x100000  4096 * 64B  = 256 KiB  (16 floats per face)
//  vattr @ 0x140000  10046*6*4B  = 236 KiB (padded region 256 KiB)
//  cnt   @ 0x180000  4096 * 4B   = 16 KiB
//  list  @ 0x184000  4096 * 256 * 2B = 2 MiB

__device__ __forceinline__ float pix_coord(int i) {
    return ((float)i + 0.5f) * 0.0078125f - 1.0f;   // exact fp32
}

__global__ __launch_bounds__(256) void k_prep(const float* __restrict__ verts,
                                              const float* __restrict__ tex,
                                              const float* __restrict__ uv,
                                              const float* __restrict__ tv,
                                              const int* __restrict__ faces,
                                              unsigned long long* __restrict__ zk,
                                              unsigned int* __restrict__ cnt,
                                              float* __restrict__ frP,
                                              float* __restrict__ vattr) {
    int blk = blockIdx.x, tid = threadIdx.x;
    if (blk < 512) {
        int i = blk * 256 + tid;
        zk[i] = (0x407FFFFFull << 32) | 0x80000000ull;   // z=-1.0, "no face"
        if (i < NB * NGRP * NT) cnt[i] = 0;
        return;
    }
    if (blk < 552) {                      // ---- per-vertex attributes ----
        int i = (blk - 512) * 256 + tid;
        if (i >= NB * NV) return;
        int b = i / NV, v = i - b * NV;
        float u = __fmul_rn(uv[2 * v + 0], 255.0f);
        float w = __fmul_rn(uv[2 * v + 1], 255.0f);
        float uf = floorf(u); uf = fminf(fmaxf(uf, 0.0f), 254.0f);
        float vf = floorf(w); vf = fminf(fmaxf(vf, 0.0f), 254.0f);
        int u0 = (int)uf, v0 = (int)vf;
        float fu = __fsub_rn(u, uf);
        float fv = __fsub_rn(w, vf);
        const float* t   = tex + (size_t)b * HWD * HWD * 3;
        const float* c00 = t + ((size_t)v0 * HWD + u0) * 3;
        const float* c01 = c00 + 3;
        const float* c10 = c00 + HWD * 3;
        const float* c11 = c10 + 3;
        float gu = 1.0f - fu, gv = 1.0f - fv;
        float* o = vattr + (size_t)i * 6;
        for (int c = 0; c < 3; ++c) {
            float l0 = c00[c] * gu + c01[c] * fu;
            float l1 = c10[c] * gu + c11[c] * fu;
            o[c] = l0 * gv + l1 * fv;
        }
        const float* vp = verts + ((size_t)b * NV + v) * 3;
        o[3] = vp[0]; o[4] = vp[1]; o[5] = vp[2];
        return;
    }
    // ---- per-face setup ----
    int i = (blk - 552) * 256 + tid;
    if (i >= NB * NF) return;
    int b = i / NF, f = i - b * NF;
    int i0 = faces[3 * f + 0], i1 = faces[3 * f + 1], i2 = faces[3 * f + 2];
    const float* base = tv + (size_t)b * NV * 3;
    float x0 = base[3 * i0 + 0], y0 = base[3 * i0 + 1], z0 = base[3 * i0 + 2];
    float x1 = base[3 * i1 + 0], y1 = base[3 * i1 + 1], z1 = base[3 * i1 + 2];
    float x2 = base[3 * i2 + 0], y2 = base[3 * i2 + 1], z2 = base[3 * i2 + 2];

    float dy12 = __fsub_rn(y1, y2);
    float dx21 = __fsub_rn(x2, x1);
    float dy20 = __fsub_rn(y2, y0);
    float dx02 = __fsub_rn(x0, x2);
    float denom = __fadd_rn(__fmul_rn(dy12, __fsub_rn(x0, x2)),
                            __fmul_rn(dx21, __fsub_rn(y0, y2)));
    bool valid = fabsf(denom) > 1e-8f;

    int xlo = 1, xhi = 0, ylo = 1, yhi = 0;
    if (valid) {
        if (fabsf(denom) < 1e-3f) {
            xlo = 0; xhi = 255; ylo = 0; yhi = 255;
        } else {
            float xmn = fminf(x0, fminf(x1, x2)), xmx = fmaxf(x0, fmaxf(x1, x2));
            float ymn = fminf(y0, fminf(y1, y2)), ymx = fmaxf(y0, fmaxf(y1, y2));
            xlo = (int)floorf((xmn + 1.0f) * 128.0f - 0.5f) - 1;
            xhi = (int)ceilf ((xmx + 1.0f) * 128.0f - 0.5f) + 1;
            ylo = (int)floorf((ymn + 1.0f) * 128.0f - 0.5f) - 1;
            yhi = (int)ceilf ((ymx + 1.0f) * 128.0f - 0.5f) + 1;
            xlo = max(xlo, 0); ylo = max(ylo, 0);
            xhi = min(xhi, 255); yhi = min(yhi, 255);
            if (xhi < xlo || yhi < ylo) { xlo = 1; xhi = 0; ylo = 1; yhi = 0; }
        }
    }
    float* o = frP + (size_t)i * 16;
    o[0] = dy12; o[1] = dx21; o[2] = x2; o[3] = y2;
    o[4] = dy20; o[5] = dx02; o[6] = valid ? (1.0f / denom) : 0.0f;
    o[7] = z0; o[8] = z1; o[9] = z2;
    ((unsigned int*)o)[10] = (unsigned)xlo | ((unsigned)xhi << 16);
    ((unsigned int*)o)[11] = (unsigned)ylo | ((unsigned)yhi << 16);
    o[12] = denom;
}

// bin faces into per-(group,tile) lists; conservative triangle-vs-tile test
__global__ __launch_bounds__(256) void k_bin(const float* __restrict__ frP,
                                             unsigned int* __restrict__ cnt,
                                             unsigned short* __restrict__ list) {
    int gi = blockIdx.x * 4 + (threadIdx.x >> 6);   // face global idx (b*NF+f)
    int lane = threadIdx.x & 63;
    int b = gi >> 11, f = gi & (NF - 1);
    int grp = f >> 8;                               // face group 0..7
    const float* o = frP + (size_t)gi * 16;
    unsigned int bbx = ((const unsigned int*)o)[10];
    unsigned int bby = ((const unsigned int*)o)[11];
    int xlo = (int)(bbx & 0xffffu), xhi = (int)(bbx >> 16);
    int ylo = (int)(bby & 0xffffu), yhi = (int)(bby >> 16);
    if (xhi < xlo || yhi < ylo) return;

    int txlo = xlo >> 4, txhi = xhi >> 4;
    int tylo = ylo >> 4, tyhi = yhi >> 4;
    int ntx = txhi - txlo + 1, nty = tyhi - tylo + 1;
    int total = ntx * nty;

    float inv = o[6], denom = o[12];
    bool skipTest = fabsf(denom) < 1e-3f;
    float x2 = o[2], y2 = o[3];
    float A0 = o[0] * inv, B0 = o[1] * inv;
    float A1 = o[4] * inv, B1 = o[5] * inv;
    float C  = A0 + A1,    D  = B0 + B1;
    unsigned int baseIdx = (unsigned)(b * NGRP + grp) << 8;

    for (int t = lane; t < total; t += 64) {
        int ty = tylo + t / ntx;
        int tx = txlo + t - (t / ntx) * ntx;
        bool keep = true;
        if (!skipTest) {
            float x0n = pix_coord(tx * 16), x1n = pix_coord(tx * 16 + 15);
            float y0n = pix_coord(ty * 16), y1n = pix_coord(ty * 16 + 15);
            float w0m = A0 * ((A0 > 0.f ? x1n : x0n) - x2) + B0 * ((B0 > 0.f ? y1n : y0n) - y2);
            float w1m = A1 * ((A1 > 0.f ? x1n : x0n) - x2) + B1 * ((B1 > 0.f ? y1n : y0n) - y2);
            float w2m = 1.0f - (C * ((C > 0.f ? x0n : x1n) - x2) + D * ((D > 0.f ? y0n : y1n) - y2));
            const float eps = 0.02f;
            keep = (w0m >= -eps) && (w1m >= -eps) && (w2m >= -eps);
        }
        if (keep) {
            unsigned int idx = baseIdx + (unsigned)(ty * 16 + tx);
            unsigned int slot = atomicAdd(&cnt[idx], 1u);
            if (slot < GRPSZ) list[((size_t)idx << 8) + slot] = (unsigned short)f;
        }
    }
}

__global__ __launch_bounds__(256) void k_raster(const float* __restrict__ frP,
                                                const unsigned int* __restrict__ cnt,
                                                const unsigned short* __restrict__ list,
                                                unsigned long long* __restrict__ zk) {
    int bid  = blockIdx.x;           // b(1) | seg(3) | tile(8)
    int tile = bid & 255;
    int seg  = (bid >> 8) & 7;
    int b    = bid >> 11;
    unsigned int idx = (unsigned)(b * NGRP + seg) << 8 | (unsigned)tile;
    unsigned int count = cnt[idx];
    if (count == 0) return;
    if (count > GRPSZ) count = GRPSZ;

    const unsigned short* lst = list + ((size_t)idx << 8);
    const float* frB = frP + ((size_t)b * NF) * 16;

    int px = ((tile & 15) << 4) + (threadIdx.x & 15);
    int py = ((tile >> 4) << 4) + (threadIdx.x >> 4);
    float pxf = pix_coord(px), pyf = pix_coord(py);

    unsigned long long best = 0ull;

    for (unsigned int j = 0; j < count; ++j) {
        int gf = __builtin_amdgcn_readfirstlane((int)lst[j]);
        const float4* fp4 = (const float4*)(frB + ((size_t)gf << 4));
        float4 qa = fp4[0];          // dy12, dx21, x2, y2
        float4 qb = fp4[1];          // dy20, dx02, inv, z0
        float4 qc = fp4[2];          // z1, z2, -, -
        float t0 = __fsub_rn(pxf, qa.z);
        float t1 = __fsub_rn(pyf, qa.w);
        float w0 = __fmul_rn(__fadd_rn(__fmul_rn(qa.x, t0), __fmul_rn(qa.y, t1)), qb.z);
        float w1 = __fmul_rn(__fadd_rn(__fmul_rn(qb.x, t0), __fmul_rn(qb.y, t1)), qb.z);
        float w2 = __fsub_rn(__fsub_rn(1.0f, w0), w1);
        if (w0 >= 0.0f && w1 >= 0.0f && w2 >= 0.0f) {
            float z = __fadd_rn(__fadd_rn(__fmul_rn(w0, qb.w), __fmul_rn(w1, qc.x)),
                                __fmul_rn(w2, qc.y));
            unsigned int ub = __float_as_uint(z);
            unsigned int hi = ub ^ ((unsigned int)(((int)ub) >> 31) | 0x80000000u);
            unsigned long long key = ((unsigned long long)hi << 32)
                                   | (unsigned long long)(0x7FFFFFFFu - (unsigned int)gf);
            best = (key > best) ? key : best;
        }
    }

    if (best) {
        int pix = (b << 16) + py * HWD + px;
        unsigned long long cur = zk[pix];
        if (best > cur) atomicMax(&zk[pix], best);
    }
}

__global__ __launch_bounds__(256) void k_shade(const unsigned long long* __restrict__ zk,
                                               const float* __restrict__ frP,
                                               const int* __restrict__ faces,
                                               const float* __restrict__ vattr,
                                               float* __restrict__ out) {
    int i = blockIdx.x * 256 + threadIdx.x;
    int b = i >> 16;
    int pix = i & 0xFFFF;
    unsigned long long key = zk[i];
    unsigned int lo = (unsigned int)key;
    unsigned int hi = (unsigned int)(key >> 32);

    float img[6] = {0, 0, 0, 0, 0, 0};
    float alpha, fidf, zout;
    if (lo > 0x7FFFFFFFu) {
        alpha = 0.0f; fidf = -1.0f; zout = -1.0f;
    } else {
        int f = (int)(0x7FFFFFFFu - lo);
        unsigned int zb32 = (hi & 0x80000000u) ? (hi & 0x7FFFFFFFu) : ~hi;
        zout = __uint_as_float(zb32);
        alpha = 1.0f;
        fidf = (float)f;
        const float* fp = frP + ((size_t)(b * NF + f)) * 16;
        int px = pix & 0xFF, py = pix >> 8;
        float t0 = __fsub_rn(pix_coord(px), fp[2]);
        float t1 = __fsub_rn(pix_coord(py), fp[3]);
        float w0 = __fmul_rn(__fadd_rn(__fmul_rn(fp[0], t0), __fmul_rn(fp[1], t1)), fp[6]);
        float w1 = __fmul_rn(__fadd_rn(__fmul_rn(fp[4], t0), __fmul_rn(fp[5], t1)), fp[6]);
        float w2 = __fsub_rn(__fsub_rn(1.0f, w0), w1);
        int i0 = faces[3 * f + 0], i1 = faces[3 * f + 1], i2 = faces[3 * f + 2];
        const float* a0 = vattr + ((size_t)b * NV + i0) * 6;
        const float* a1 = vattr + ((size_t)b * NV + i1) * 6;
        const float* a2 = vattr + ((size_t)b * NV + i2) * 6;
        for (int c = 0; c < 6; ++c)
            img[c] = __fadd_rn(__fadd_rn(__fmul_rn(w0, a0[c]), __fmul_rn(w1, a1[c])),
                               __fmul_rn(w2, a2[c]));
    }

    const size_t plane = (size_t)HWD * HWD;
    for (int c = 0; c < 6; ++c)
        out[((size_t)b * 6 + c) * plane + pix] = img[c];
    out[786432 + i]  = alpha;
    out[917504 + i]  = fidf;
    out[1048576 + i] = zout;
}

extern "C" void kernel_launch(void* const* d_in, const int* in_sizes, int n_in,
                              void* d_out, int out_size, void* d_ws, size_t ws_size,
                              hipStream_t stream) {
    (void)in_sizes; (void)n_in; (void)out_size; (void)ws_size;
    const float* verts = (const float*)d_in[0];
    const float* tv    = (const float*)d_in[1];
    const float* tex   = (const float*)d_in[2];
    const float* uv    = (const float*)d_in[3];
    const int*   faces = (const int*)d_in[4];
    float* out = (float*)d_out;

    char* ws = (char*)d_ws;
    unsigned long long* zk    = (unsigned long long*)ws;            // 1 MiB
    float*              frP   = (float*)(ws + 0x100000);            // 256 KiB
    float*              vattr = (float*)(ws + 0x140000);            // 256 KiB
    unsigned int*       cnt   = (unsigned int*)(ws + 0x180000);     // 16 KiB
    unsigned short*     list  = (unsigned short*)(ws + 0x184000);   // 2 MiB

    k_prep  <<<568, 256, 0, stream>>>(verts, tex, uv, tv, faces, zk, cnt, frP, vattr);
    k_bin   <<<NB * NF / 4, 256, 0, stream>>>(frP, cnt, list);
    k_raster<<<NB * NGRP * NT, 256, 0, stream>>>(frP, cnt, list, zk);
    k_shade <<<512, 256, 0, stream>>>(zk, frP, faces, vattr, out);
}